// Round 3
// baseline (430.162 us; speedup 1.0000x reference)
//
#include <hip/hip_runtime.h>

typedef __attribute__((ext_vector_type(8))) short short8;
typedef __attribute__((ext_vector_type(4))) float float4v;
typedef __attribute__((ext_vector_type(4))) int int4v;

#define E_EDGES 300000
#define TAB_ELEMS 12800000                      // 100000 nodes x 128 feats
#define NTILES 9375                             // 300000 / 32 exactly
#define DBLK 128                                // persistent blocks per type
#define NWAVESTOT (DBLK * 16)                   // 2048 waves per type

__device__ __forceinline__ short f2bf(float f) {
    unsigned u = __float_as_uint(f);
    return (short)((u + 0x7FFFu + ((u >> 16) & 1u)) >> 16);
}
__device__ __forceinline__ unsigned pk_bf16(float a, float b) {
    unsigned ua = __float_as_uint(a), ub = __float_as_uint(b);
    ua += 0x7FFFu + ((ua >> 16) & 1u);
    ub += 0x7FFFu + ((ub >> 16) & 1u);
    return __builtin_amdgcn_perm(ub, ua, 0x07060302);
}
__device__ __forceinline__ void cp16(const void* g, void* l) {
    __builtin_amdgcn_global_load_lds(
        (const __attribute__((address_space(1))) unsigned int*)g,
        (__attribute__((address_space(3))) unsigned int*)l, 16, 0, 0);
}

// ws layout (shorts):
//   [0..98304)            weight tiles [n][k] in 64-k tiles, chunk-XOR swizzled
//   [98304..+12.8M)       user_emb bf16
//   [..+25.6M)            item_emb bf16
__global__ void prep_all(const float* __restrict__ ue, const float* __restrict__ ie,
                         const float* __restrict__ Wbi_ui, const float* __restrict__ W1_ui,
                         const float* __restrict__ Wbi_iu, const float* __restrict__ W1_iu,
                         short* __restrict__ ws) {
    __shared__ short tr[64 * 68];
    const int t = blockIdx.y;
    const int tid = threadIdx.x;
    if (blockIdx.x < 1024) {                    // ---- streaming table conversion ----
        const float* src = t ? ie : ue;
        short* dst = ws + 98304 + (size_t)t * TAB_ELEMS;
        const int stride = 1024 * 256;
        for (int g = blockIdx.x * 256 + tid; g < TAB_ELEMS / 8; g += stride) {
            const float* p = src + (size_t)g * 8;
            float4v v0 = ((const float4v*)p)[0];
            float4v v1 = ((const float4v*)p)[1];
            int4v w = { (int)pk_bf16(v0[0], v0[1]), (int)pk_bf16(v0[2], v0[3]),
                        (int)pk_bf16(v1[0], v1[1]), (int)pk_bf16(v1[2], v1[3]) };
            *(int4v*)(dst + (size_t)g * 8) = w;
        }
        return;
    }
    // ---- weight transpose + swizzle (12 tiles per type) ----
    const int m = blockIdx.x - 1024;            // 0..11
    const float* W; int k0, n0, obase;
    if (m < 8) {                                // Wbi (K=256, N=128)
        int kt = m >> 1, nh = m & 1;
        W = t ? Wbi_iu : Wbi_ui; k0 = kt * 64; n0 = nh * 64;
        obase = t * 32768 + kt * 8192;
    } else {                                    // W1 (K=128, N=128)
        int mm = m - 8; int kt = mm >> 1, nh = mm & 1;
        W = t ? W1_iu : W1_ui; k0 = kt * 64; n0 = nh * 64;
        obase = 65536 + t * 16384 + kt * 8192;
    }
    for (int it = 0; it < 16; ++it) {
        int flat = it * 256 + tid;
        int kk = flat >> 6, nn = flat & 63;
        tr[nn * 68 + kk] = f2bf(W[(size_t)(k0 + kk) * 128 + n0 + nn]);
    }
    __syncthreads();
    for (int it = 0; it < 16; ++it) {
        int flat = it * 256 + tid;
        int nn = flat >> 6, kk = flat & 63;
        int n = n0 + nn;
        ws[obase + n * 64 + (kk ^ ((n & 7) << 3))] = tr[nn * 68 + kk];
    }
}

// Persistent-weight decoder: 1 block of 1024 threads per CU (grid 128 x 2 types).
// Weights staged to LDS ONCE (Wbi 64 KB + W1 32 KB), biases/W2 in registers once;
// 16 waves grid-stride over 32-edge tiles with ZERO barriers in the steady loop.
// H-transpose uses 2 KB/wave (epilogue-1 split into two 64-col halves, each
// consumed into a2 regs before overwrite). LDS = 128 KiB exactly -> 1 block/CU,
// occupancy LDS-bound -> VGPRs free: full a[2][8] gather, pipelined 1 tile ahead.
template<bool BF16G>
__launch_bounds__(1024)
__global__ void edge_decoder(
    const float* __restrict__ user_emb, const float* __restrict__ item_emb,
    const int* __restrict__ ei_ui, const int* __restrict__ ei_iu,
    const float* __restrict__ b_bi_ui, const float* __restrict__ b1_ui,
    const float* __restrict__ W2_ui, const float* __restrict__ b2_ui,
    const float* __restrict__ b_bi_iu, const float* __restrict__ b1_iu,
    const float* __restrict__ W2_iu, const float* __restrict__ b2_iu,
    const short* __restrict__ ws, const short* __restrict__ tab,
    float* __restrict__ out)
{
    __shared__ short WL[6 * 8192];              // 96 KiB: Wbi tiles 0..3, W1 tiles 0..1
    __shared__ short HL[16 * 1024];             // 32 KiB: 2 KB per wave (16x64 half-H)

    const int type = blockIdx.y;
    const int tid = threadIdx.x;
    const int wave = tid >> 6, lane = tid & 63;
    const int q = lane >> 4, ln = lane & 15;

    const int*   ei   = type ? ei_iu : ei_ui;
    const float* bbi  = type ? b_bi_iu : b_bi_ui;
    const float* b1v  = type ? b1_iu : b1_ui;
    const float* W2v  = type ? W2_iu : W2_ui;
    const float* b2v  = type ? b2_iu : b2_ui;
    const short* WbiT = ws + type * 32768;
    const short* W1T  = ws + 65536 + type * 16384;
    const short* tabS = tab + (size_t)(type ? TAB_ELEMS : 0);
    const short* tabD = tab + (size_t)(type ? 0 : TAB_ELEMS);
    const float* srcT = type ? item_emb : user_emb;
    const float* dstT = type ? user_emb : item_emb;

    // ---- one-time: stage all 6 weight tiles (1 cp16/thread/tile) ----
    #pragma unroll
    for (int c = 0; c < 6; ++c) {
        const short* src = (c < 4) ? (WbiT + c * 8192) : (W1T + (c - 4) * 8192);
        cp16(src + tid * 8, &WL[c * 8192 + tid * 8]);
    }

    // ---- one-time: biases + W2 into registers ----
    float bb0[8], bb1[8], w2r[8];
    #pragma unroll
    for (int nt = 0; nt < 8; ++nt) {
        bb0[nt] = bbi[nt * 16 + ln];
        bb1[nt] = b1v[nt * 16 + ln];
        w2r[nt] = W2v[nt * 16 + ln];
    }
    const float b2s = b2v[0];

    __syncthreads();                            // weights resident; no barriers after

    const int swz = (ln & 7) << 3;
    const int t0 = blockIdx.x * 16 + wave;
    short* Hw = &HL[wave * 1024];

    int siN[2], diN[2];
    short8 a[2][8];

#define LOADIDX(T) do { \
    int tt = (T) < NTILES ? (T) : 0; \
    _Pragma("unroll") \
    for (int mt = 0; mt < 2; ++mt) { \
        int e = tt * 32 + mt * 16 + ln; \
        siN[mt] = ei[e]; diN[mt] = ei[E_EDGES + e]; \
    } } while (0)

#define GATHER_A() do { \
    if (BF16G) { \
        _Pragma("unroll") \
        for (int mt = 0; mt < 2; ++mt) { \
            const short* sp = tabS + (size_t)siN[mt] * 128 + q * 8; \
            const short* dp = tabD + (size_t)diN[mt] * 128 + q * 8; \
            _Pragma("unroll") \
            for (int ks = 0; ks < 4; ++ks) a[mt][ks] = *(const short8*)(sp + ks * 32); \
            _Pragma("unroll") \
            for (int ks = 0; ks < 4; ++ks) a[mt][4 + ks] = *(const short8*)(dp + ks * 32); \
        } \
    } else { \
        _Pragma("unroll") \
        for (int mt = 0; mt < 2; ++mt) { \
            const float* sp = srcT + (size_t)siN[mt] * 128 + q * 8; \
            const float* dp = dstT + (size_t)diN[mt] * 128 + q * 8; \
            _Pragma("unroll") \
            for (int ks = 0; ks < 8; ++ks) { \
                const float* p = (ks < 4) ? (sp + ks * 32) : (dp + (ks - 4) * 32); \
                float4v v0 = ((const float4v*)p)[0]; \
                float4v v1 = ((const float4v*)p)[1]; \
                int4v wv = { (int)pk_bf16(v0[0], v0[1]), (int)pk_bf16(v0[2], v0[3]), \
                             (int)pk_bf16(v1[0], v1[1]), (int)pk_bf16(v1[2], v1[3]) }; \
                a[mt][ks] = *(short8*)&wv; \
            } \
        } \
    } } while (0)

    // ---- pipeline prologue ----
    LOADIDX(t0);
    GATHER_A();                                 // tile t0
    LOADIDX(t0 + NWAVESTOT);                    // indices one tile ahead

    for (int t = t0; t < NTILES; t += NWAVESTOT) {
        // acc init = bias (column-only -> all 4 row-elems identical)
        float4v acc[2][8];
        #pragma unroll
        for (int nt = 0; nt < 8; ++nt) {
            acc[0][nt] = (float4v){bb0[nt], bb0[nt], bb0[nt], bb0[nt]};
            acc[1][nt] = acc[0][nt];
        }

        // ---- Layer 1: K=256, 4 resident tiles, no barriers ----
        __builtin_amdgcn_s_setprio(1);
        #pragma unroll
        for (int kt = 0; kt < 4; ++kt) {
            #pragma unroll
            for (int ks2 = 0; ks2 < 2; ++ks2) {
                const int ka = (ks2 * 32 + q * 8) ^ swz;
                #pragma unroll
                for (int nt = 0; nt < 8; ++nt) {
                    short8 bf = *(const short8*)&WL[kt * 8192 + (nt * 16 + ln) * 64 + ka];
                    acc[0][nt] = __builtin_amdgcn_mfma_f32_16x16x32_bf16(a[0][kt * 2 + ks2], bf, acc[0][nt], 0, 0, 0);
                    acc[1][nt] = __builtin_amdgcn_mfma_f32_16x16x32_bf16(a[1][kt * 2 + ks2], bf, acc[1][nt], 0, 0, 0);
                }
            }
        }
        __builtin_amdgcn_s_setprio(0);

        // ---- prefetch next tile: a[] is dead; ~1500 cyc of epi/L2 hides latency ----
        GATHER_A();                             // tile t+NWAVESTOT (indices resident)
        LOADIDX(t + 2 * NWAVESTOT);             // indices two tiles ahead

        // ---- Epilogue 1: ELU -> bf16 H, per-mt and per-64-col-half (2 KB buffer) ----
        // XOR group swizzle: 16B group g of row r at g ^ (r&7); read side 2-way free.
        short8 a2[2][4];
        #pragma unroll
        for (int mt = 0; mt < 2; ++mt) {
            #pragma unroll
            for (int h = 0; h < 2; ++h) {
                #pragma unroll
                for (int nt2 = 0; nt2 < 4; ++nt2) {
                    float4v v = acc[mt][h * 4 + nt2];
                    #pragma unroll
                    for (int r = 0; r < 4; ++r) {
                        float x = v[r];
                        float hh = x > 0.f ? x : (__expf(x) - 1.f);
                        int row = q * 4 + r;
                        int g = (nt2 * 2 + (ln >> 3)) ^ (row & 7);
                        Hw[row * 64 + g * 8 + (ln & 7)] = f2bf(hh);
                    }
                }
                // consume half into regs (same-wave LDS RAW; compiler waits lgkmcnt)
                #pragma unroll
                for (int ks2 = 0; ks2 < 2; ++ks2) {
                    int g = (ks2 * 4 + q) ^ (ln & 7);
                    a2[mt][h * 2 + ks2] = *(const short8*)&Hw[ln * 64 + g * 8];
                }
            }
        }

        #pragma unroll
        for (int nt = 0; nt < 8; ++nt) {
            acc[0][nt] = (float4v){bb1[nt], bb1[nt], bb1[nt], bb1[nt]};
            acc[1][nt] = acc[0][nt];
        }

        // ---- Layer 2: K=128, 2 resident tiles ----
        __builtin_amdgcn_s_setprio(1);
        #pragma unroll
        for (int kt = 0; kt < 2; ++kt) {
            #pragma unroll
            for (int ks2 = 0; ks2 < 2; ++ks2) {
                const int ka = (ks2 * 32 + q * 8) ^ swz;
                #pragma unroll
                for (int nt = 0; nt < 8; ++nt) {
                    short8 bf = *(const short8*)&WL[(4 + kt) * 8192 + (nt * 16 + ln) * 64 + ka];
                    acc[0][nt] = __builtin_amdgcn_mfma_f32_16x16x32_bf16(a2[0][kt * 2 + ks2], bf, acc[0][nt], 0, 0, 0);
                    acc[1][nt] = __builtin_amdgcn_mfma_f32_16x16x32_bf16(a2[1][kt * 2 + ks2], bf, acc[1][nt], 0, 0, 0);
                }
            }
        }
        __builtin_amdgcn_s_setprio(0);

        // ---- Epilogue 2: ELU, dot W2, 16-lane reduce, sigmoid, store ----
        #pragma unroll
        for (int mt = 0; mt < 2; ++mt) {
            float s0 = 0.f, s1 = 0.f, s2 = 0.f, s3 = 0.f;
            #pragma unroll
            for (int nt = 0; nt < 8; ++nt) {
                float wv = w2r[nt];
                float4v v = acc[mt][nt];
                float x;
                x = v[0]; x = x > 0.f ? x : (__expf(x) - 1.f); s0 += x * wv;
                x = v[1]; x = x > 0.f ? x : (__expf(x) - 1.f); s1 += x * wv;
                x = v[2]; x = x > 0.f ? x : (__expf(x) - 1.f); s2 += x * wv;
                x = v[3]; x = x > 0.f ? x : (__expf(x) - 1.f); s3 += x * wv;
            }
            #pragma unroll
            for (int off = 1; off < 16; off <<= 1) {
                s0 += __shfl_xor(s0, off);
                s1 += __shfl_xor(s1, off);
                s2 += __shfl_xor(s2, off);
                s3 += __shfl_xor(s3, off);
            }
            if (ln < 4) {
                float sv = (ln == 0) ? s0 : (ln == 1) ? s1 : (ln == 2) ? s2 : s3;
                int e = t * 32 + mt * 16 + q * 4 + ln;   // E_EDGES = 32*NTILES exactly
                float z = sv + b2s;
                out[type * E_EDGES + e] = 1.f / (1.f + __expf(-z));
            }
        }
    }
#undef LOADIDX
#undef GATHER_A
}

extern "C" void kernel_launch(void* const* d_in, const int* in_sizes, int n_in,
                              void* d_out, int out_size, void* d_ws, size_t ws_size,
                              hipStream_t stream) {
    const float* user_emb = (const float*)d_in[0];
    const float* item_emb = (const float*)d_in[1];
    const int*   ei_ui    = (const int*)d_in[2];
    const int*   ei_iu    = (const int*)d_in[3];
    const float* W_bi_ui  = (const float*)d_in[4];
    const float* b_bi_ui  = (const float*)d_in[5];
    const float* W1_ui    = (const float*)d_in[6];
    const float* b1_ui    = (const float*)d_in[7];
    const float* W2_ui    = (const float*)d_in[8];
    const float* b2_ui    = (const float*)d_in[9];
    const float* W_bi_iu  = (const float*)d_in[10];
    const float* b_bi_iu  = (const float*)d_in[11];
    const float* W1_iu    = (const float*)d_in[12];
    const float* b1_iu    = (const float*)d_in[13];
    const float* W2_iu    = (const float*)d_in[14];
    const float* b2_iu    = (const float*)d_in[15];
    short* ws  = (short*)d_ws;
    short* tab = ws + 98304;
    float* out = (float*)d_out;

    const size_t need = 98304u * 2u + (size_t)2 * TAB_ELEMS * 2u;  // 51.4 MB

    hipLaunchKernelGGL(prep_all, dim3(1036, 2), dim3(256), 0, stream,
                       user_emb, item_emb, W_bi_ui, W1_ui, W_bi_iu, W1_iu, ws);
    if (ws_size >= need) {
        edge_decoder<true><<<dim3(DBLK, 2), dim3(1024), 0, stream>>>(
            user_emb, item_emb, ei_ui, ei_iu,
            b_bi_ui, b1_ui, W2_ui, b2_ui,
            b_bi_iu, b1_iu, W2_iu, b2_iu,
            ws, tab, out);
    } else {
        edge_decoder<false><<<dim3(DBLK, 2), dim3(1024), 0, stream>>>(
            user_emb, item_emb, ei_ui, ei_iu,
            b_bi_ui, b1_ui, W2_ui, b2_ui,
            b_bi_iu, b1_iu, W2_iu, b2_iu,
            ws, tab, out);
    }
}

// Round 4
// 263.603 us; speedup vs baseline: 1.6319x; 1.6319x over previous
//
#include <hip/hip_runtime.h>

typedef __attribute__((ext_vector_type(8))) short short8;
typedef __attribute__((ext_vector_type(4))) float float4v;
typedef __attribute__((ext_vector_type(4))) int int4v;

#define E_EDGES 300000
#define TAB_ELEMS 12800000                      // 100000 nodes x 128 feats
#define NTILES 9375                             // 300000 / 32 exactly
#define DBLK 256                                // persistent blocks per type
#define WPB 8                                   // waves per block (512 threads)
#define NWAVESTOT (DBLK * WPB)                  // 2048 waves per type

__device__ __forceinline__ short f2bf(float f) {
    unsigned u = __float_as_uint(f);
    return (short)((u + 0x7FFFu + ((u >> 16) & 1u)) >> 16);
}
__device__ __forceinline__ unsigned pk_bf16(float a, float b) {
    unsigned ua = __float_as_uint(a), ub = __float_as_uint(b);
    ua += 0x7FFFu + ((ua >> 16) & 1u);
    ub += 0x7FFFu + ((ub >> 16) & 1u);
    return __builtin_amdgcn_perm(ub, ua, 0x07060302);
}
__device__ __forceinline__ void cp16(const void* g, void* l) {
    __builtin_amdgcn_global_load_lds(
        (const __attribute__((address_space(1))) unsigned int*)g,
        (__attribute__((address_space(3))) unsigned int*)l, 16, 0, 0);
}

// ws layout (shorts):
//   [0..98304)            weight tiles [n][k] in 64-k tiles, chunk-XOR swizzled
//   [98304..+12.8M)       user_emb bf16
//   [..+25.6M)            item_emb bf16
__global__ void prep_all(const float* __restrict__ ue, const float* __restrict__ ie,
                         const float* __restrict__ Wbi_ui, const float* __restrict__ W1_ui,
                         const float* __restrict__ Wbi_iu, const float* __restrict__ W1_iu,
                         short* __restrict__ ws) {
    __shared__ short tr[64 * 68];
    const int t = blockIdx.y;
    const int tid = threadIdx.x;
    if (blockIdx.x < 1024) {                    // ---- streaming table conversion ----
        const float* src = t ? ie : ue;
        short* dst = ws + 98304 + (size_t)t * TAB_ELEMS;
        const int stride = 1024 * 256;
        for (int g = blockIdx.x * 256 + tid; g < TAB_ELEMS / 8; g += stride) {
            const float* p = src + (size_t)g * 8;
            float4v v0 = ((const float4v*)p)[0];
            float4v v1 = ((const float4v*)p)[1];
            int4v w = { (int)pk_bf16(v0[0], v0[1]), (int)pk_bf16(v0[2], v0[3]),
                        (int)pk_bf16(v1[0], v1[1]), (int)pk_bf16(v1[2], v1[3]) };
            *(int4v*)(dst + (size_t)g * 8) = w;
        }
        return;
    }
    // ---- weight transpose + swizzle (12 tiles per type) ----
    const int m = blockIdx.x - 1024;            // 0..11
    const float* W; int k0, n0, obase;
    if (m < 8) {                                // Wbi (K=256, N=128)
        int kt = m >> 1, nh = m & 1;
        W = t ? Wbi_iu : Wbi_ui; k0 = kt * 64; n0 = nh * 64;
        obase = t * 32768 + kt * 8192;
    } else {                                    // W1 (K=128, N=128)
        int mm = m - 8; int kt = mm >> 1, nh = mm & 1;
        W = t ? W1_iu : W1_ui; k0 = kt * 64; n0 = nh * 64;
        obase = 65536 + t * 16384 + kt * 8192;
    }
    for (int it = 0; it < 16; ++it) {
        int flat = it * 256 + tid;
        int kk = flat >> 6, nn = flat & 63;
        tr[nn * 68 + kk] = f2bf(W[(size_t)(k0 + kk) * 128 + n0 + nn]);
    }
    __syncthreads();
    for (int it = 0; it < 16; ++it) {
        int flat = it * 256 + tid;
        int nn = flat >> 6, kk = flat & 63;
        int n = n0 + nn;
        ws[obase + n * 64 + (kk ^ ((n & 7) << 3))] = tr[nn * 68 + kk];
    }
}

// Persistent-weight decoder, spill-free cell: 512-thread blocks (8 waves),
// LDS = 96 KiB weights + 16 KiB H = 112 KiB -> 1 block/CU -> 2 waves/SIMD ->
// register cap 256/thread (demand ~175: acc 64 AGPR + a 32 + a2 32 + hoisted
// 24 + addr). Round-3's 1024-thread version capped at 128 and spilled 387 MB.
// __launch_bounds__(512, 2) pins the RA target. Weights staged ONCE per block;
// ZERO barriers in the steady loop; gather prefetched 1 tile ahead (hidden
// under epilogue-1 + layer-2), indices 2 ahead.
template<bool BF16G>
__launch_bounds__(512, 2)
__global__ void edge_decoder(
    const float* __restrict__ user_emb, const float* __restrict__ item_emb,
    const int* __restrict__ ei_ui, const int* __restrict__ ei_iu,
    const float* __restrict__ b_bi_ui, const float* __restrict__ b1_ui,
    const float* __restrict__ W2_ui, const float* __restrict__ b2_ui,
    const float* __restrict__ b_bi_iu, const float* __restrict__ b1_iu,
    const float* __restrict__ W2_iu, const float* __restrict__ b2_iu,
    const short* __restrict__ ws, const short* __restrict__ tab,
    float* __restrict__ out)
{
    __shared__ short WL[6 * 8192];              // 96 KiB: Wbi tiles 0..3, W1 tiles 0..1
    __shared__ short HL[WPB * 1024];            // 16 KiB: 2 KiB per wave (16x64 half-H)

    const int type = blockIdx.y;
    const int tid = threadIdx.x;
    const int wave = tid >> 6, lane = tid & 63;
    const int q = lane >> 4, ln = lane & 15;

    const int*   ei   = type ? ei_iu : ei_ui;
    const float* bbi  = type ? b_bi_iu : b_bi_ui;
    const float* b1v  = type ? b1_iu : b1_ui;
    const float* W2v  = type ? W2_iu : W2_ui;
    const float* b2v  = type ? b2_iu : b2_ui;
    const short* WbiT = ws + type * 32768;
    const short* W1T  = ws + 65536 + type * 16384;
    const short* tabS = tab + (size_t)(type ? TAB_ELEMS : 0);
    const short* tabD = tab + (size_t)(type ? 0 : TAB_ELEMS);
    const float* srcT = type ? item_emb : user_emb;
    const float* dstT = type ? user_emb : item_emb;

    // ---- one-time: stage all 6 weight tiles (12 x 8 KiB cp16 rounds) ----
    #pragma unroll
    for (int c = 0; c < 12; ++c) {
        int tl = c >> 1;
        const short* src = ((tl < 4) ? (WbiT + tl * 8192) : (W1T + (tl - 4) * 8192))
                         + (c & 1) * 4096;
        cp16(src + tid * 8, &WL[tl * 8192 + (c & 1) * 4096 + tid * 8]);
    }

    // ---- one-time: biases + W2 into registers ----
    float bb0[8], bb1[8], w2r[8];
    #pragma unroll
    for (int nt = 0; nt < 8; ++nt) {
        bb0[nt] = bbi[nt * 16 + ln];
        bb1[nt] = b1v[nt * 16 + ln];
        w2r[nt] = W2v[nt * 16 + ln];
    }
    const float b2s = b2v[0];

    __syncthreads();                            // weights resident; no barriers after

    const int swz = (ln & 7) << 3;
    const int t0 = blockIdx.x * WPB + wave;
    short* Hw = &HL[wave * 1024];

    int siN[2], diN[2];
    short8 a[2][8];

#define LOADIDX(T) do { \
    int tt = (T) < NTILES ? (T) : 0; \
    _Pragma("unroll") \
    for (int mt = 0; mt < 2; ++mt) { \
        int e = tt * 32 + mt * 16 + ln; \
        siN[mt] = ei[e]; diN[mt] = ei[E_EDGES + e]; \
    } } while (0)

#define GATHER_A() do { \
    if (BF16G) { \
        _Pragma("unroll") \
        for (int mt = 0; mt < 2; ++mt) { \
            const short* sp = tabS + (size_t)siN[mt] * 128 + q * 8; \
            const short* dp = tabD + (size_t)diN[mt] * 128 + q * 8; \
            _Pragma("unroll") \
            for (int ks = 0; ks < 4; ++ks) a[mt][ks] = *(const short8*)(sp + ks * 32); \
            _Pragma("unroll") \
            for (int ks = 0; ks < 4; ++ks) a[mt][4 + ks] = *(const short8*)(dp + ks * 32); \
        } \
    } else { \
        _Pragma("unroll") \
        for (int mt = 0; mt < 2; ++mt) { \
            const float* sp = srcT + (size_t)siN[mt] * 128 + q * 8; \
            const float* dp = dstT + (size_t)diN[mt] * 128 + q * 8; \
            _Pragma("unroll") \
            for (int ks = 0; ks < 8; ++ks) { \
                const float* p = (ks < 4) ? (sp + ks * 32) : (dp + (ks - 4) * 32); \
                float4v v0 = ((const float4v*)p)[0]; \
                float4v v1 = ((const float4v*)p)[1]; \
                int4v wv = { (int)pk_bf16(v0[0], v0[1]), (int)pk_bf16(v0[2], v0[3]), \
                             (int)pk_bf16(v1[0], v1[1]), (int)pk_bf16(v1[2], v1[3]) }; \
                a[mt][ks] = *(short8*)&wv; \
            } \
        } \
    } } while (0)

    // ---- pipeline prologue ----
    LOADIDX(t0);
    GATHER_A();                                 // tile t0
    LOADIDX(t0 + NWAVESTOT);                    // indices one tile ahead

    for (int t = t0; t < NTILES; t += NWAVESTOT) {
        // acc init = bias (column-only -> all 4 row-elems identical)
        float4v acc[2][8];
        #pragma unroll
        for (int nt = 0; nt < 8; ++nt) {
            acc[0][nt] = (float4v){bb0[nt], bb0[nt], bb0[nt], bb0[nt]};
            acc[1][nt] = acc[0][nt];
        }

        // ---- Layer 1: K=256, 4 resident tiles, no barriers ----
        __builtin_amdgcn_s_setprio(1);
        #pragma unroll
        for (int kt = 0; kt < 4; ++kt) {
            #pragma unroll
            for (int ks2 = 0; ks2 < 2; ++ks2) {
                const int ka = (ks2 * 32 + q * 8) ^ swz;
                #pragma unroll
                for (int nt = 0; nt < 8; ++nt) {
                    short8 bf = *(const short8*)&WL[kt * 8192 + (nt * 16 + ln) * 64 + ka];
                    acc[0][nt] = __builtin_amdgcn_mfma_f32_16x16x32_bf16(a[0][kt * 2 + ks2], bf, acc[0][nt], 0, 0, 0);
                    acc[1][nt] = __builtin_amdgcn_mfma_f32_16x16x32_bf16(a[1][kt * 2 + ks2], bf, acc[1][nt], 0, 0, 0);
                }
            }
        }
        __builtin_amdgcn_s_setprio(0);

        // ---- prefetch next tile: a[] is dead; epilogue-1 + L2 hides latency ----
        GATHER_A();                             // tile t+NWAVESTOT (indices resident)
        LOADIDX(t + 2 * NWAVESTOT);             // indices two tiles ahead

        // ---- Epilogue 1: ELU -> bf16 H, per-mt and per-64-col-half (2 KiB) ----
        // XOR group swizzle: 16B group g of row r at g ^ (r&7); read side 2-way free.
        short8 a2[2][4];
        #pragma unroll
        for (int mt = 0; mt < 2; ++mt) {
            #pragma unroll
            for (int h = 0; h < 2; ++h) {
                #pragma unroll
                for (int nt2 = 0; nt2 < 4; ++nt2) {
                    float4v v = acc[mt][h * 4 + nt2];
                    #pragma unroll
                    for (int r = 0; r < 4; ++r) {
                        float x = v[r];
                        float hh = x > 0.f ? x : (__expf(x) - 1.f);
                        int row = q * 4 + r;
                        int g = (nt2 * 2 + (ln >> 3)) ^ (row & 7);
                        Hw[row * 64 + g * 8 + (ln & 7)] = f2bf(hh);
                    }
                }
                // consume half into regs (same-wave LDS RAW; compiler waits lgkmcnt)
                #pragma unroll
                for (int ks2 = 0; ks2 < 2; ++ks2) {
                    int g = (ks2 * 4 + q) ^ (ln & 7);
                    a2[mt][h * 2 + ks2] = *(const short8*)&Hw[ln * 64 + g * 8];
                }
            }
        }

        #pragma unroll
        for (int nt = 0; nt < 8; ++nt) {
            acc[0][nt] = (float4v){bb1[nt], bb1[nt], bb1[nt], bb1[nt]};
            acc[1][nt] = acc[0][nt];
        }

        // ---- Layer 2: K=128, 2 resident tiles ----
        __builtin_amdgcn_s_setprio(1);
        #pragma unroll
        for (int kt = 0; kt < 2; ++kt) {
            #pragma unroll
            for (int ks2 = 0; ks2 < 2; ++ks2) {
                const int ka = (ks2 * 32 + q * 8) ^ swz;
                #pragma unroll
                for (int nt = 0; nt < 8; ++nt) {
                    short8 bf = *(const short8*)&WL[(4 + kt) * 8192 + (nt * 16 + ln) * 64 + ka];
                    acc[0][nt] = __builtin_amdgcn_mfma_f32_16x16x32_bf16(a2[0][kt * 2 + ks2], bf, acc[0][nt], 0, 0, 0);
                    acc[1][nt] = __builtin_amdgcn_mfma_f32_16x16x32_bf16(a2[1][kt * 2 + ks2], bf, acc[1][nt], 0, 0, 0);
                }
            }
        }
        __builtin_amdgcn_s_setprio(0);

        // ---- Epilogue 2: ELU, dot W2, 16-lane reduce, sigmoid, store ----
        #pragma unroll
        for (int mt = 0; mt < 2; ++mt) {
            float s0 = 0.f, s1 = 0.f, s2 = 0.f, s3 = 0.f;
            #pragma unroll
            for (int nt = 0; nt < 8; ++nt) {
                float wv = w2r[nt];
                float4v v = acc[mt][nt];
                float x;
                x = v[0]; x = x > 0.f ? x : (__expf(x) - 1.f); s0 += x * wv;
                x = v[1]; x = x > 0.f ? x : (__expf(x) - 1.f); s1 += x * wv;
                x = v[2]; x = x > 0.f ? x : (__expf(x) - 1.f); s2 += x * wv;
                x = v[3]; x = x > 0.f ? x : (__expf(x) - 1.f); s3 += x * wv;
            }
            #pragma unroll
            for (int off = 1; off < 16; off <<= 1) {
                s0 += __shfl_xor(s0, off);
                s1 += __shfl_xor(s1, off);
                s2 += __shfl_xor(s2, off);
                s3 += __shfl_xor(s3, off);
            }
            if (ln < 4) {
                float sv = (ln == 0) ? s0 : (ln == 1) ? s1 : (ln == 2) ? s2 : s3;
                int e = t * 32 + mt * 16 + q * 4 + ln;   // E_EDGES = 32*NTILES exactly
                float z = sv + b2s;
                out[type * E_EDGES + e] = 1.f / (1.f + __expf(-z));
            }
        }
    }
#undef LOADIDX
#undef GATHER_A
}

extern "C" void kernel_launch(void* const* d_in, const int* in_sizes, int n_in,
                              void* d_out, int out_size, void* d_ws, size_t ws_size,
                              hipStream_t stream) {
    const float* user_emb = (const float*)d_in[0];
    const float* item_emb = (const float*)d_in[1];
    const int*   ei_ui    = (const int*)d_in[2];
    const int*   ei_iu    = (const int*)d_in[3];
    const float* W_bi_ui  = (const float*)d_in[4];
    const float* b_bi_ui  = (const float*)d_in[5];
    const float* W1_ui    = (const float*)d_in[6];
    const float* b1_ui    = (const float*)d_in[7];
    const float* W2_ui    = (const float*)d_in[8];
    const float* b2_ui    = (const float*)d_in[9];
    const float* W_bi_iu  = (const float*)d_in[10];
    const float* b_bi_iu  = (const float*)d_in[11];
    const float* W1_iu    = (const float*)d_in[12];
    const float* b1_iu    = (const float*)d_in[13];
    const float* W2_iu    = (const float*)d_in[14];
    const float* b2_iu    = (const float*)d_in[15];
    short* ws  = (short*)d_ws;
    short* tab = ws + 98304;
    float* out = (float*)d_out;

    const size_t need = 98304u * 2u + (size_t)2 * TAB_ELEMS * 2u;  // 51.4 MB

    hipLaunchKernelGGL(prep_all, dim3(1036, 2), dim3(256), 0, stream,
                       user_emb, item_emb, W_bi_ui, W1_ui, W_bi_iu, W1_iu, ws);
    if (ws_size >= need) {
        edge_decoder<true><<<dim3(DBLK, 2), dim3(512), 0, stream>>>(
            user_emb, item_emb, ei_ui, ei_iu,
            b_bi_ui, b1_ui, W2_ui, b2_ui,
            b_bi_iu, b1_iu, W2_iu, b2_iu,
            ws, tab, out);
    } else {
        edge_decoder<false><<<dim3(DBLK, 2), dim3(512), 0, stream>>>(
            user_emb, item_emb, ei_ui, ei_iu,
            b_bi_ui, b1_ui, W2_ui, b2_ui,
            b_bi_iu, b1_iu, W2_iu, b2_iu,
            ws, tab, out);
    }
}

// Round 5
// 239.435 us; speedup vs baseline: 1.7966x; 1.1009x over previous
//
#include <hip/hip_runtime.h>

typedef __attribute__((ext_vector_type(8))) short short8;
typedef __attribute__((ext_vector_type(4))) float float4v;
typedef __attribute__((ext_vector_type(4))) int int4v;
typedef __attribute__((ext_vector_type(2))) int int2v;

#define E_EDGES 300000
#define EPB 128                                 // edges per block (32 per wave)
#define NBLK ((E_EDGES + EPB - 1) / EPB)        // 2344 blocks per edge type
#define TAB_ELEMS 12800000                      // 100000 nodes x 128 feats

__device__ __forceinline__ short f2bf(float f) {
    unsigned u = __float_as_uint(f);
    return (short)((u + 0x7FFFu + ((u >> 16) & 1u)) >> 16);
}
__device__ __forceinline__ unsigned pk_bf16(float a, float b) {
    unsigned ua = __float_as_uint(a), ub = __float_as_uint(b);
    ua += 0x7FFFu + ((ua >> 16) & 1u);
    ub += 0x7FFFu + ((ub >> 16) & 1u);
    return __builtin_amdgcn_perm(ub, ua, 0x07060302);
}
// HW RNE pack of two f32 -> one u32 of 2 bf16 (lo = a, hi = b). Same rounding
// as pk_bf16 but 1 instruction instead of ~7. No builtin on gfx950 (T12/m240).
__device__ __forceinline__ unsigned cvtpk(float a, float b) {
    unsigned r;
    __asm__("v_cvt_pk_bf16_f32 %0, %1, %2" : "=v"(r) : "v"(a), "v"(b));
    return r;
}
__device__ __forceinline__ void cp16(const void* g, void* l) {
    __builtin_amdgcn_global_load_lds(
        (const __attribute__((address_space(1))) unsigned int*)g,
        (__attribute__((address_space(3))) unsigned int*)l, 16, 0, 0);
}

// ws layout (shorts):
//   [0..98304)            weight tiles [n][k] in 64-k tiles, chunk-XOR swizzled
//   [98304..+12.8M)       user_emb bf16
//   [..+25.6M)            item_emb bf16
__global__ void prep_all(const float* __restrict__ ue, const float* __restrict__ ie,
                         const float* __restrict__ Wbi_ui, const float* __restrict__ W1_ui,
                         const float* __restrict__ Wbi_iu, const float* __restrict__ W1_iu,
                         short* __restrict__ ws) {
    __shared__ short tr[64 * 68];
    const int t = blockIdx.y;
    const int tid = threadIdx.x;
    if (blockIdx.x < 1024) {                    // ---- streaming table conversion ----
        const float* src = t ? ie : ue;
        short* dst = ws + 98304 + (size_t)t * TAB_ELEMS;
        const int stride = 1024 * 256;
        for (int g = blockIdx.x * 256 + tid; g < TAB_ELEMS / 8; g += stride) {
            const float* p = src + (size_t)g * 8;
            float4v v0 = ((const float4v*)p)[0];
            float4v v1 = ((const float4v*)p)[1];
            int4v w = { (int)pk_bf16(v0[0], v0[1]), (int)pk_bf16(v0[2], v0[3]),
                        (int)pk_bf16(v1[0], v1[1]), (int)pk_bf16(v1[2], v1[3]) };
            *(int4v*)(dst + (size_t)g * 8) = w;
        }
        return;
    }
    // ---- weight transpose + swizzle (12 tiles per type) ----
    const int m = blockIdx.x - 1024;            // 0..11
    const float* W; int k0, n0, obase;
    if (m < 8) {                                // Wbi (K=256, N=128)
        int kt = m >> 1, nh = m & 1;
        W = t ? Wbi_iu : Wbi_ui; k0 = kt * 64; n0 = nh * 64;
        obase = t * 32768 + kt * 8192;
    } else {                                    // W1 (K=128, N=128)
        int mm = m - 8; int kt = mm >> 1, nh = mm & 1;
        W = t ? W1_iu : W1_ui; k0 = kt * 64; n0 = nh * 64;
        obase = 65536 + t * 16384 + kt * 8192;
    }
    for (int it = 0; it < 16; ++it) {
        int flat = it * 256 + tid;
        int kk = flat >> 6, nn = flat & 63;
        tr[nn * 68 + kk] = f2bf(W[(size_t)(k0 + kk) * 128 + n0 + nn]);
    }
    __syncthreads();
    for (int it = 0; it < 16; ++it) {
        int flat = it * 256 + tid;
        int nn = flat >> 6, kk = flat & 63;
        int n = n0 + nn;
        ws[obase + n * 64 + (kk ^ ((n & 7) << 3))] = tr[nn * 68 + kk];
    }
}

// Round-2 cell (EPB 128, 4 blocks/CU, dbuf weights, ping-pong gather) + T12
// operand swap: mfma(W_frag, edge_frag, acc) -> D has col=edge(ln), row=n-sub
// (4q+r). Each lane owns 4 CONSECUTIVE n of its own edge =>
//   - bias init = one float4 load
//   - epi1 pack = v_cvt_pk_bf16_f32 pairs + ds_write_b64 (was 64 b16 writes +
//     256 pack-VALU)
//   - epi2 n-reduce = in-lane + 2 shfl_xor (was 32 shfl + select chain)
// H LDS swizzle on 8B groups: g ^ (2(ln&7) | (ln&8)); reads stay 16B-aligned
// and contiguous (XOR is even), conflicts <= 4-way.
template<bool BF16G>
__launch_bounds__(256, 4)
__global__ void edge_decoder(
    const float* __restrict__ user_emb, const float* __restrict__ item_emb,
    const int* __restrict__ ei_ui, const int* __restrict__ ei_iu,
    const float* __restrict__ b_bi_ui, const float* __restrict__ b1_ui,
    const float* __restrict__ W2_ui, const float* __restrict__ b2_ui,
    const float* __restrict__ b_bi_iu, const float* __restrict__ b1_iu,
    const float* __restrict__ W2_iu, const float* __restrict__ b2_iu,
    const short* __restrict__ ws, const short* __restrict__ tab,
    float* __restrict__ out)
{
    __shared__ short Blds[2][128 * 64];         // 32768 B total (double buffer)

    const int type = blockIdx.y;
    const int e0 = blockIdx.x * EPB;
    const int tid = threadIdx.x;
    const int wave = tid >> 6, lane = tid & 63;
    const int q = lane >> 4, ln = lane & 15;

    const int*   ei   = type ? ei_iu : ei_ui;
    const float* bbi  = type ? b_bi_iu : b_bi_ui;
    const float* b1v  = type ? b1_iu : b1_ui;
    const float* W2v  = type ? W2_iu : W2_ui;
    const float* b2v  = type ? b2_iu : b2_ui;
    const short* WbiT = ws + type * 32768;
    const short* W1T  = ws + 65536 + type * 16384;

    // DMA weight tile 0 -> buf0 immediately (overlaps index load + gather)
    #pragma unroll
    for (int c = 0; c < 4; ++c)
        cp16(WbiT + c * 2048 + tid * 8, &Blds[0][c * 2048 + tid * 8]);

    // two edges per lane (M-tiles mt=0,1); edge-in-tile = ln
    int si[2], di[2];
    #pragma unroll
    for (int mt = 0; mt < 2; ++mt) {
        int erow = e0 + wave * 32 + mt * 16 + ln;
        int safe = (erow < E_EDGES) ? erow : 0;
        si[mt] = ei[safe];
        di[mt] = ei[E_EDGES + safe];
    }

    const short* sp[2]; const short* dp[2];     // bf16-table path
    const float* spf[2]; const float* dpf[2];   // fp32 fallback path
    if (BF16G) {
        #pragma unroll
        for (int mt = 0; mt < 2; ++mt) {
            sp[mt] = tab + (size_t)(type ? TAB_ELEMS : 0) + (size_t)si[mt] * 128 + q * 8;
            dp[mt] = tab + (size_t)(type ? 0 : TAB_ELEMS) + (size_t)di[mt] * 128 + q * 8;
        }
    } else {
        const float* srcT = type ? item_emb : user_emb;
        const float* dstT = type ? user_emb : item_emb;
        #pragma unroll
        for (int mt = 0; mt < 2; ++mt) {
            spf[mt] = srcT + (size_t)si[mt] * 128 + q * 8;
            dpf[mt] = dstT + (size_t)di[mt] * 128 + q * 8;
        }
    }

    short8 aA[2][2], aB[2][2];                  // ping-pong per-tile edge fragments

#define GATHER(BUF, HALF, OFF) do { \
    _Pragma("unroll") \
    for (int mt = 0; mt < 2; ++mt) { \
        _Pragma("unroll") \
        for (int k2 = 0; k2 < 2; ++k2) { \
            if (BF16G) { \
                BUF[mt][k2] = *(const short8*)((HALF ? dp[mt] : sp[mt]) + OFF + k2 * 32); \
            } else { \
                const float* p = (HALF ? dpf[mt] : spf[mt]) + OFF + k2 * 32; \
                float4v v0 = ((const float4v*)p)[0]; \
                float4v v1 = ((const float4v*)p)[1]; \
                int4v w = { (int)pk_bf16(v0[0], v0[1]), (int)pk_bf16(v0[2], v0[3]), \
                            (int)pk_bf16(v1[0], v1[1]), (int)pk_bf16(v1[2], v1[3]) }; \
                BUF[mt][k2] = *(short8*)&w; \
            } \
        } \
    } } while (0)

    GATHER(aA, 0, 0);                           // tile 0: src[0:64)
    GATHER(aB, 0, 64);                          // tile 1: src[64:128)

    // acc init = bias; swapped D => rows are n = 16nt+4q+r -> one float4 load
    float4v acc[2][8];
    #pragma unroll
    for (int nt = 0; nt < 8; ++nt) {
        acc[0][nt] = *(const float4v*)(bbi + nt * 16 + q * 4);
        acc[1][nt] = acc[0][nt];
    }

    const int swz = (ln & 7) << 3;              // weight-tile 16B-chunk xor
    const int hswz = ((ln & 7) << 1) | (ln & 8); // H 8B-group xor (even -> keeps
                                                 // b64/b128 contiguity+alignment)

// One layer-1 K-tile, SWAPPED operands: mfma(W_frag, edge_frag, acc).
#define L1_TILE(KT, ABUF) do { \
    __syncthreads(); \
    const short* nxt = (KT < 3) ? (WbiT + (KT + 1) * 8192) : W1T; \
    _Pragma("unroll") \
    for (int c = 0; c < 4; ++c) \
        cp16(nxt + c * 2048 + tid * 8, &Blds[(KT + 1) & 1][c * 2048 + tid * 8]); \
    __builtin_amdgcn_s_setprio(1); \
    _Pragma("unroll") \
    for (int ks2 = 0; ks2 < 2; ++ks2) { \
        int ka = (ks2 * 32 + q * 8) ^ swz; \
        _Pragma("unroll") \
        for (int nt = 0; nt < 8; ++nt) { \
            short8 bf = *(const short8*)&Blds[KT & 1][(nt * 16 + ln) * 64 + ka]; \
            acc[0][nt] = __builtin_amdgcn_mfma_f32_16x16x32_bf16(bf, ABUF[0][ks2], acc[0][nt], 0, 0, 0); \
            acc[1][nt] = __builtin_amdgcn_mfma_f32_16x16x32_bf16(bf, ABUF[1][ks2], acc[1][nt], 0, 0, 0); \
        } \
    } \
    __builtin_amdgcn_s_setprio(0); \
    } while (0)

    // ---- Layer 1: K=256 concat [src|dst], 4 tiles of 64-K ----
    L1_TILE(0, aA);
    GATHER(aA, 1, 0);                           // tile 2: dst[0:64)
    L1_TILE(1, aB);
    GATHER(aB, 1, 64);                          // tile 3: dst[64:128)
    L1_TILE(2, aA);
    L1_TILE(3, aB);                             // stages W1 tile0 -> buf0

    __syncthreads();                            // W1t0 resident; buf1 free -> H

    // ---- Epilogue 1: ELU -> packed bf16 H rows in buf1 (per-wave 4 KiB) ----
    // Lane (q,ln) holds edge=ln, n=16nt+4q+{0..3}: 2 cvt_pk + 1 ds_write_b64.
    // Read back B-fragments for layer 2: H[ln][32ks+8q..+7], 16B swizzled reads.
    short* Hw = &Blds[1][wave * 2048];
    short8 a2[2][4];
    #pragma unroll
    for (int mt = 0; mt < 2; ++mt) {
        #pragma unroll
        for (int nt = 0; nt < 8; ++nt) {
            float4v v = acc[mt][nt];
            float x0 = v[0] > 0.f ? v[0] : (__expf(v[0]) - 1.f);
            float x1 = v[1] > 0.f ? v[1] : (__expf(v[1]) - 1.f);
            float x2 = v[2] > 0.f ? v[2] : (__expf(v[2]) - 1.f);
            float x3 = v[3] > 0.f ? v[3] : (__expf(v[3]) - 1.f);
            int g = (4 * nt + q) ^ hswz;
            *(int2v*)(Hw + ln * 128 + g * 4) =
                (int2v){ (int)cvtpk(x0, x1), (int)cvtpk(x2, x3) };
        }
        // same-wave LDS RAW; compiler inserts lgkmcnt wait
        #pragma unroll
        for (int ks = 0; ks < 4; ++ks) {
            int g = (8 * ks + 2 * q) ^ hswz;
            a2[mt][ks] = *(const short8*)(Hw + ln * 128 + g * 4);
        }
    }

    #pragma unroll
    for (int nt = 0; nt < 8; ++nt) {
        acc[0][nt] = *(const float4v*)(b1v + nt * 16 + q * 4);
        acc[1][nt] = acc[0][nt];
    }

    __syncthreads();                            // all waves done reading their H
    #pragma unroll
    for (int c = 0; c < 4; ++c)                 // stage W1 tile1 -> buf1
        cp16(W1T + 8192 + c * 2048 + tid * 8, &Blds[1][c * 2048 + tid * 8]);

#define L2_TILE(KT) do { \
    if (KT == 1) __syncthreads(); \
    __builtin_amdgcn_s_setprio(1); \
    _Pragma("unroll") \
    for (int ks2 = 0; ks2 < 2; ++ks2) { \
        int ka = (ks2 * 32 + q * 8) ^ swz; \
        _Pragma("unroll") \
        for (int nt = 0; nt < 8; ++nt) { \
            short8 bf = *(const short8*)&Blds[KT][(nt * 16 + ln) * 64 + ka]; \
            acc[0][nt] = __builtin_amdgcn_mfma_f32_16x16x32_bf16(bf, a2[0][KT * 2 + ks2], acc[0][nt], 0, 0, 0); \
            acc[1][nt] = __builtin_amdgcn_mfma_f32_16x16x32_bf16(bf, a2[1][KT * 2 + ks2], acc[1][nt], 0, 0, 0); \
        } \
    } \
    __builtin_amdgcn_s_setprio(0); \
    } while (0)

    // ---- Layer 2: K=128, 2 tiles ----
    L2_TILE(0);
    L2_TILE(1);

    // ---- Epilogue 2: ELU, dot W2 (in-lane), 2-shfl reduce, sigmoid, store ----
    float4v w2q[8];
    #pragma unroll
    for (int nt = 0; nt < 8; ++nt)
        w2q[nt] = *(const float4v*)(W2v + nt * 16 + q * 4);
    const float b2s = b2v[0];

    #pragma unroll
    for (int mt = 0; mt < 2; ++mt) {
        float s = 0.f;
        #pragma unroll
        for (int nt = 0; nt < 8; ++nt) {
            float4v v = acc[mt][nt];
            float4v w = w2q[nt];
            float x;
            x = v[0]; x = x > 0.f ? x : (__expf(x) - 1.f); s += x * w[0];
            x = v[1]; x = x > 0.f ? x : (__expf(x) - 1.f); s += x * w[1];
            x = v[2]; x = x > 0.f ? x : (__expf(x) - 1.f); s += x * w[2];
            x = v[3]; x = x > 0.f ? x : (__expf(x) - 1.f); s += x * w[3];
        }
        s += __shfl_xor(s, 16);
        s += __shfl_xor(s, 32);
        if (q == mt) {
            int e = e0 + wave * 32 + mt * 16 + ln;
            if (e < E_EDGES) {
                float z = s + b2s;
                out[type * E_EDGES + e] = 1.f / (1.f + __expf(-z));
            }
        }
    }
#undef GATHER
#undef L1_TILE
#undef L2_TILE
}

extern "C" void kernel_launch(void* const* d_in, const int* in_sizes, int n_in,
                              void* d_out, int out_size, void* d_ws, size_t ws_size,
                              hipStream_t stream) {
    const float* user_emb = (const float*)d_in[0];
    const float* item_emb = (const float*)d_in[1];
    const int*   ei_ui    = (const int*)d_in[2];
    const int*   ei_iu    = (const int*)d_in[3];
    const float* W_bi_ui  = (const float*)d_in[4];
    const float* b_bi_ui  = (const float*)d_in[5];
    const float* W1_ui    = (const float*)d_in[6];
    const float* b1_ui    = (const float*)d_in[7];
    const float* W2_ui    = (const float*)d_in[8];
    const float* b2_ui    = (const float*)d_in[9];
    const float* W_bi_iu  = (const float*)d_in[10];
    const float* b_bi_iu  = (const float*)d_in[11];
    const float* W1_iu    = (const float*)d_in[12];
    const float* b1_iu    = (const float*)d_in[13];
    const float* W2_iu    = (const float*)d_in[14];
    const float* b2_iu    = (const float*)d_in[15];
    short* ws  = (short*)d_ws;
    short* tab = ws + 98304;
    float* out = (float*)d_out;

    const size_t need = 98304u * 2u + (size_t)2 * TAB_ELEMS * 2u;  // 51.4 MB

    hipLaunchKernelGGL(prep_all, dim3(1036, 2), dim3(256), 0, stream,
                       user_emb, item_emb, W_bi_ui, W1_ui, W_bi_iu, W1_iu, ws);
    if (ws_size >= need) {
        edge_decoder<true><<<dim3(NBLK, 2), dim3(256), 0, stream>>>(
            user_emb, item_emb, ei_ui, ei_iu,
            b_bi_ui, b1_ui, W2_ui, b2_ui,
            b_bi_iu, b1_iu, W2_iu, b2_iu,
            ws, tab, out);
    } else {
        edge_decoder<false><<<dim3(NBLK, 2), dim3(256), 0, stream>>>(
            user_emb, item_emb, ei_ui, ei_iu,
            b_bi_ui, b1_ui, W2_ui, b2_ui,
            b_bi_iu, b1_iu, W2_iu, b2_iu,
            ws, tab, out);
    }
}

// Round 6
// 236.716 us; speedup vs baseline: 1.8172x; 1.0115x over previous
//
#include <hip/hip_runtime.h>

typedef __attribute__((ext_vector_type(8))) short short8;
typedef __attribute__((ext_vector_type(4))) float float4v;
typedef __attribute__((ext_vector_type(4))) int int4v;
typedef __attribute__((ext_vector_type(2))) int int2v;

#define E_EDGES 300000
#define EPB 256                                 // edges per block (32 per wave, 8 waves)
#define NBLK ((E_EDGES + EPB - 1) / EPB)        // 1172 blocks per edge type
#define TAB_ELEMS 12800000                      // 100000 nodes x 128 feats

__device__ __forceinline__ short f2bf(float f) {
    unsigned u = __float_as_uint(f);
    return (short)((u + 0x7FFFu + ((u >> 16) & 1u)) >> 16);
}
__device__ __forceinline__ unsigned pk_bf16(float a, float b) {
    unsigned ua = __float_as_uint(a), ub = __float_as_uint(b);
    ua += 0x7FFFu + ((ua >> 16) & 1u);
    ub += 0x7FFFu + ((ub >> 16) & 1u);
    return __builtin_amdgcn_perm(ub, ua, 0x07060302);
}
// HW RNE pack of two f32 -> one u32 of 2 bf16 (lo = a, hi = b).
__device__ __forceinline__ unsigned cvtpk(float a, float b) {
    unsigned r;
    __asm__("v_cvt_pk_bf16_f32 %0, %1, %2" : "=v"(r) : "v"(a), "v"(b));
    return r;
}
__device__ __forceinline__ void cp16(const void* g, void* l) {
    __builtin_amdgcn_global_load_lds(
        (const __attribute__((address_space(1))) unsigned int*)g,
        (__attribute__((address_space(3))) unsigned int*)l, 16, 0, 0);
}

// ws layout (shorts):
//   [0..98304)            weight tiles [n][k] in 64-k tiles, chunk-XOR swizzled
//   [98304..+12.8M)       user_emb bf16
//   [..+25.6M)            item_emb bf16
__global__ void prep_all(const float* __restrict__ ue, const float* __restrict__ ie,
                         const float* __restrict__ Wbi_ui, const float* __restrict__ W1_ui,
                         const float* __restrict__ Wbi_iu, const float* __restrict__ W1_iu,
                         short* __restrict__ ws) {
    __shared__ short tr[64 * 68];
    const int t = blockIdx.y;
    const int tid = threadIdx.x;
    if (blockIdx.x < 1024) {                    // ---- streaming table conversion ----
        const float* src = t ? ie : ue;
        short* dst = ws + 98304 + (size_t)t * TAB_ELEMS;
        const int stride = 1024 * 256;
        for (int g = blockIdx.x * 256 + tid; g < TAB_ELEMS / 8; g += stride) {
            const float* p = src + (size_t)g * 8;
            float4v v0 = ((const float4v*)p)[0];
            float4v v1 = ((const float4v*)p)[1];
            int4v w = { (int)pk_bf16(v0[0], v0[1]), (int)pk_bf16(v0[2], v0[3]),
                        (int)pk_bf16(v1[0], v1[1]), (int)pk_bf16(v1[2], v1[3]) };
            *(int4v*)(dst + (size_t)g * 8) = w;
        }
        return;
    }
    // ---- weight transpose + swizzle (12 tiles per type) ----
    const int m = blockIdx.x - 1024;            // 0..11
    const float* W; int k0, n0, obase;
    if (m < 8) {                                // Wbi (K=256, N=128)
        int kt = m >> 1, nh = m & 1;
        W = t ? Wbi_iu : Wbi_ui; k0 = kt * 64; n0 = nh * 64;
        obase = t * 32768 + kt * 8192;
    } else {                                    // W1 (K=128, N=128)
        int mm = m - 8; int kt = mm >> 1, nh = mm & 1;
        W = t ? W1_iu : W1_ui; k0 = kt * 64; n0 = nh * 64;
        obase = 65536 + t * 16384 + kt * 8192;
    }
    for (int it = 0; it < 16; ++it) {
        int flat = it * 256 + tid;
        int kk = flat >> 6, nn = flat & 63;
        tr[nn * 68 + kk] = f2bf(W[(size_t)(k0 + kk) * 128 + n0 + nn]);
    }
    __syncthreads();
    for (int it = 0; it < 16; ++it) {
        int flat = it * 256 + tid;
        int nn = flat >> 6, kk = flat & 63;
        int n = n0 + nn;
        ws[obase + n * 64 + (kk ^ ((n & 7) << 3))] = tr[nn * 68 + kk];
    }
}

// Round-5 wave-level code (T12 operand swap, verified numerics) re-shaped to
// 8-wave / EPB=256 blocks: barriers per 256 edges 14 -> 6, weight-staging
// rounds per edge halved, weight L2 traffic 450 -> 225 MB. H lives in a
// dedicated 32 KiB HL (4 KiB/wave, private -> its barrier dies too).
// LDS = 32 KiB dbuf + 32 KiB HL = 64 KiB -> 2 blocks/CU; launch_bounds(512,4)
// -> 128-reg cap, identical per-thread state as round 5 (no new spill).
template<bool BF16G>
__launch_bounds__(512, 4)
__global__ void edge_decoder(
    const float* __restrict__ user_emb, const float* __restrict__ item_emb,
    const int* __restrict__ ei_ui, const int* __restrict__ ei_iu,
    const float* __restrict__ b_bi_ui, const float* __restrict__ b1_ui,
    const float* __restrict__ W2_ui, const float* __restrict__ b2_ui,
    const float* __restrict__ b_bi_iu, const float* __restrict__ b1_iu,
    const float* __restrict__ W2_iu, const float* __restrict__ b2_iu,
    const short* __restrict__ ws, const short* __restrict__ tab,
    float* __restrict__ out)
{
    __shared__ short Blds[2][128 * 64];         // 32 KiB weight double buffer
    __shared__ short HL[8 * 2048];              // 32 KiB H (4 KiB per wave)

    const int type = blockIdx.y;
    const int tid = threadIdx.x;
    const int wave = tid >> 6, lane = tid & 63;
    const int q = lane >> 4, ln = lane & 15;
    const int e0 = blockIdx.x * EPB;

    const int*   ei   = type ? ei_iu : ei_ui;
    const float* bbi  = type ? b_bi_iu : b_bi_ui;
    const float* b1v  = type ? b1_iu : b1_ui;
    const float* W2v  = type ? W2_iu : W2_ui;
    const float* b2v  = type ? b2_iu : b2_ui;
    const short* WbiT = ws + type * 32768;
    const short* W1T  = ws + 65536 + type * 16384;

    // DMA weight tile 0 -> buf0 immediately (overlaps index load + gather)
    #pragma unroll
    for (int c = 0; c < 2; ++c)
        cp16(WbiT + c * 4096 + tid * 8, &Blds[0][c * 4096 + tid * 8]);

    // two edges per lane (M-tiles mt=0,1); edge-in-tile = ln
    int si[2], di[2];
    #pragma unroll
    for (int mt = 0; mt < 2; ++mt) {
        int erow = e0 + wave * 32 + mt * 16 + ln;
        int safe = (erow < E_EDGES) ? erow : 0;
        si[mt] = ei[safe];
        di[mt] = ei[E_EDGES + safe];
    }

    const short* sp[2]; const short* dp[2];     // bf16-table path
    const float* spf[2]; const float* dpf[2];   // fp32 fallback path
    if (BF16G) {
        #pragma unroll
        for (int mt = 0; mt < 2; ++mt) {
            sp[mt] = tab + (size_t)(type ? TAB_ELEMS : 0) + (size_t)si[mt] * 128 + q * 8;
            dp[mt] = tab + (size_t)(type ? 0 : TAB_ELEMS) + (size_t)di[mt] * 128 + q * 8;
        }
    } else {
        const float* srcT = type ? item_emb : user_emb;
        const float* dstT = type ? user_emb : item_emb;
        #pragma unroll
        for (int mt = 0; mt < 2; ++mt) {
            spf[mt] = srcT + (size_t)si[mt] * 128 + q * 8;
            dpf[mt] = dstT + (size_t)di[mt] * 128 + q * 8;
        }
    }

    short8 aA[2][2], aB[2][2];                  // ping-pong per-tile edge fragments

#define GATHER(BUF, HALF, OFF) do { \
    _Pragma("unroll") \
    for (int mt = 0; mt < 2; ++mt) { \
        _Pragma("unroll") \
        for (int k2 = 0; k2 < 2; ++k2) { \
            if (BF16G) { \
                BUF[mt][k2] = *(const short8*)((HALF ? dp[mt] : sp[mt]) + OFF + k2 * 32); \
            } else { \
                const float* p = (HALF ? dpf[mt] : spf[mt]) + OFF + k2 * 32; \
                float4v v0 = ((const float4v*)p)[0]; \
                float4v v1 = ((const float4v*)p)[1]; \
                int4v w = { (int)pk_bf16(v0[0], v0[1]), (int)pk_bf16(v0[2], v0[3]), \
                            (int)pk_bf16(v1[0], v1[1]), (int)pk_bf16(v1[2], v1[3]) }; \
                BUF[mt][k2] = *(short8*)&w; \
            } \
        } \
    } } while (0)

    GATHER(aA, 0, 0);                           // tile 0: src[0:64)
    GATHER(aB, 0, 64);                          // tile 1: src[64:128)

    // acc init = bias; swapped D => rows are n = 16nt+4q+r -> one float4 load
    float4v acc[2][8];
    #pragma unroll
    for (int nt = 0; nt < 8; ++nt) {
        acc[0][nt] = *(const float4v*)(bbi + nt * 16 + q * 4);
        acc[1][nt] = acc[0][nt];
    }

    const int swz = (ln & 7) << 3;              // weight-tile 16B-chunk xor
    const int hswz = ((ln & 7) << 1) | (ln & 8); // H 8B-group xor

// One layer-1 K-tile, SWAPPED operands: mfma(W_frag, edge_frag, acc).
#define L1_TILE(KT, ABUF) do { \
    __syncthreads(); \
    const short* nxt = (KT < 3) ? (WbiT + (KT + 1) * 8192) : W1T; \
    _Pragma("unroll") \
    for (int c = 0; c < 2; ++c) \
        cp16(nxt + c * 4096 + tid * 8, &Blds[(KT + 1) & 1][c * 4096 + tid * 8]); \
    __builtin_amdgcn_s_setprio(1); \
    _Pragma("unroll") \
    for (int ks2 = 0; ks2 < 2; ++ks2) { \
        int ka = (ks2 * 32 + q * 8) ^ swz; \
        _Pragma("unroll") \
        for (int nt = 0; nt < 8; ++nt) { \
            short8 bf = *(const short8*)&Blds[KT & 1][(nt * 16 + ln) * 64 + ka]; \
            acc[0][nt] = __builtin_amdgcn_mfma_f32_16x16x32_bf16(bf, ABUF[0][ks2], acc[0][nt], 0, 0, 0); \
            acc[1][nt] = __builtin_amdgcn_mfma_f32_16x16x32_bf16(bf, ABUF[1][ks2], acc[1][nt], 0, 0, 0); \
        } \
    } \
    __builtin_amdgcn_s_setprio(0); \
    } while (0)

    // ---- Layer 1: K=256 concat [src|dst], 4 tiles of 64-K ----
    L1_TILE(0, aA);
    GATHER(aA, 1, 0);                           // tile 2: dst[0:64)
    L1_TILE(1, aB);
    GATHER(aB, 1, 64);                          // tile 3: dst[64:128)
    L1_TILE(2, aA);
    L1_TILE(3, aB);                             // stages W1 tile0 -> buf0

    __syncthreads();                            // W1t0 resident; buf1 free

    // stage W1 tile1 -> buf1 NOW: DMA flies under the whole epilogue-1 VALU phase
    #pragma unroll
    for (int c = 0; c < 2; ++c)
        cp16(W1T + 8192 + c * 4096 + tid * 8, &Blds[1][c * 4096 + tid * 8]);

    // ---- Epilogue 1: ELU -> packed bf16 H rows in private HL (4 KiB/wave) ----
    // Lane (q,ln) holds edge=ln, n=16nt+4q+{0..3}: 2 cvt_pk + 1 ds_write_b64.
    short* Hw = &HL[wave * 2048];
    short8 a2[2][4];
    #pragma unroll
    for (int mt = 0; mt < 2; ++mt) {
        #pragma unroll
        for (int nt = 0; nt < 8; ++nt) {
            float4v v = acc[mt][nt];
            float x0 = v[0] > 0.f ? v[0] : (__expf(v[0]) - 1.f);
            float x1 = v[1] > 0.f ? v[1] : (__expf(v[1]) - 1.f);
            float x2 = v[2] > 0.f ? v[2] : (__expf(v[2]) - 1.f);
            float x3 = v[3] > 0.f ? v[3] : (__expf(v[3]) - 1.f);
            int g = (4 * nt + q) ^ hswz;
            *(int2v*)(Hw + ln * 128 + g * 4) =
                (int2v){ (int)cvtpk(x0, x1), (int)cvtpk(x2, x3) };
        }
        // same-wave LDS RAW; compiler inserts lgkmcnt wait
        #pragma unroll
        for (int ks = 0; ks < 4; ++ks) {
            int g = (8 * ks + 2 * q) ^ hswz;
            a2[mt][ks] = *(const short8*)(Hw + ln * 128 + g * 4);
        }
    }

    #pragma unroll
    for (int nt = 0; nt < 8; ++nt) {
        acc[0][nt] = *(const float4v*)(b1v + nt * 16 + q * 4);
        acc[1][nt] = acc[0][nt];
    }

#define L2_TILE(KT) do { \
    if (KT == 1) __syncthreads(); \
    __builtin_amdgcn_s_setprio(1); \
    _Pragma("unroll") \
    for (int ks2 = 0; ks2 < 2; ++ks2) { \
        int ka = (ks2 * 32 + q * 8) ^ swz; \
        _Pragma("unroll") \
        for (int nt = 0; nt < 8; ++nt) { \
            short8 bf = *(const short8*)&Blds[KT][(nt * 16 + ln) * 64 + ka]; \
            acc[0][nt] = __builtin_amdgcn_mfma_f32_16x16x32_bf16(bf, a2[0][KT * 2 + ks2], acc[0][nt], 0, 0, 0); \
            acc[1][nt] = __builtin_amdgcn_mfma_f32_16x16x32_bf16(bf, a2[1][KT * 2 + ks2], acc[1][nt], 0, 0, 0); \
        } \
    } \
    __builtin_amdgcn_s_setprio(0); \
    } while (0)

    // ---- Layer 2: K=128, 2 tiles ----
    L2_TILE(0);                                 // buf0 (covered by the post-L1 barrier)
    L2_TILE(1);                                 // barrier: W1t1 resident in buf1

    // ---- Epilogue 2: ELU, dot W2 (in-lane), 2-shfl reduce, sigmoid, store ----
    float4v w2q[8];
    #pragma unroll
    for (int nt = 0; nt < 8; ++nt)
        w2q[nt] = *(const float4v*)(W2v + nt * 16 + q * 4);
    const float b2s = b2v[0];

    #pragma unroll
    for (int mt = 0; mt < 2; ++mt) {
        float s = 0.f;
        #pragma unroll
        for (int nt = 0; nt < 8; ++nt) {
            float4v v = acc[mt][nt];
            float4v w = w2q[nt];
            float x;
            x = v[0]; x = x > 0.f ? x : (__expf(x) - 1.f); s += x * w[0];
            x = v[1]; x = x > 0.f ? x : (__expf(x) - 1.f); s += x * w[1];
            x = v[2]; x = x > 0.f ? x : (__expf(x) - 1.f); s += x * w[2];
            x = v[3]; x = x > 0.f ? x : (__expf(x) - 1.f); s += x * w[3];
        }
        s += __shfl_xor(s, 16);
        s += __shfl_xor(s, 32);
        if (q == mt) {
            int e = e0 + wave * 32 + mt * 16 + ln;
            if (e < E_EDGES) {
                float z = s + b2s;
                out[type * E_EDGES + e] = 1.f / (1.f + __expf(-z));
            }
        }
    }
#undef GATHER
#undef L1_TILE
#undef L2_TILE
}

extern "C" void kernel_launch(void* const* d_in, const int* in_sizes, int n_in,
                              void* d_out, int out_size, void* d_ws, size_t ws_size,
                              hipStream_t stream) {
    const float* user_emb = (const float*)d_in[0];
    const float* item_emb = (const float*)d_in[1];
    const int*   ei_ui    = (const int*)d_in[2];
    const int*   ei_iu    = (const int*)d_in[3];
    const float* W_bi_ui  = (const float*)d_in[4];
    const float* b_bi_ui  = (const float*)d_in[5];
    const float* W1_ui    = (const float*)d_in[6];
    const float* b1_ui    = (const float*)d_in[7];
    const float* W2_ui    = (const float*)d_in[8];
    const float* b2_ui    = (const float*)d_in[9];
    const float* W_bi_iu  = (const float*)d_in[10];
    const float* b_bi_iu  = (const float*)d_in[11];
    const float* W1_iu    = (const float*)d_in[12];
    const float* b1_iu    = (const float*)d_in[13];
    const float* W2_iu    = (const float*)d_in[14];
    const float* b2_iu    = (const float*)d_in[15];
    short* ws  = (short*)d_ws;
    short* tab = ws + 98304;
    float* out = (float*)d_out;

    const size_t need = 98304u * 2u + (size_t)2 * TAB_ELEMS * 2u;  // 51.4 MB

    hipLaunchKernelGGL(prep_all, dim3(1036, 2), dim3(256), 0, stream,
                       user_emb, item_emb, W_bi_ui, W1_ui, W_bi_iu, W1_iu, ws);
    if (ws_size >= need) {
        edge_decoder<true><<<dim3(NBLK, 2), dim3(512), 0, stream>>>(
            user_emb, item_emb, ei_ui, ei_iu,
            b_bi_ui, b1_ui, W2_ui, b2_ui,
            b_bi_iu, b1_iu, W2_iu, b2_iu,
            ws, tab, out);
    } else {
        edge_decoder<false><<<dim3(NBLK, 2), dim3(512), 0, stream>>>(
            user_emb, item_emb, ei_ui, ei_iu,
            b_bi_ui, b1_ui, W2_ui, b2_ui,
            b_bi_iu, b1_iu, W2_iu, b2_iu,
            ws, tab, out);
    }
}